// Round 1
// baseline (327.305 us; speedup 1.0000x reference)
//
#include <hip/hip_runtime.h>

#define B_ROWS   16384
#define K_NB     64
#define D_DIM    256
#define TWO_D    512
#define R_BLK    8          // rows per block
#define THREADS  256

// __launch_bounds__(256, 4): license up to 128 VGPR (4 waves/EU) so the dual-row
// 16-deep gather pipeline is not register-clamped back to 8-deep. LDS (19 KB)
// would allow 8 blocks/CU but VGPR will cap us at ~4-5 — intentional ILP-for-TLP trade.
__global__ __launch_bounds__(THREADS, 4)
void easyrec_fused(const int* __restrict__ nodes_u,
                   const int* __restrict__ nodes_v,
                   const int* __restrict__ neighbors,
                   const int* __restrict__ neighbor_counts,
                   const float* __restrict__ u2e,
                   const float* __restrict__ v2e,
                   const float* __restrict__ W,      // [D, 2D] row-major
                   const float* __restrict__ bias,   // [D]
                   float* __restrict__ out)          // [B]
{
    __shared__ __align__(16) int   nbr_lds[R_BLK * K_NB];     // 2 KB
    __shared__ __align__(16) float cat_lds[R_BLK][TWO_D];     // 16 KB: [self | nmean]
    __shared__ float red_lds[R_BLK * 4];
    __shared__ float selfdot_lds[R_BLK];
    __shared__ float bdot_lds[R_BLK];

    const int t    = threadIdx.x;
    const int wave = t >> 6;
    const int lane = t & 63;
    const int row0 = blockIdx.x * R_BLK;

    // ---- stage neighbor indices for the 8 rows (512 ints, coalesced) ----
    nbr_lds[t]           = neighbors[(size_t)row0 * K_NB + t];
    nbr_lds[t + THREADS] = neighbors[(size_t)row0 * K_NB + t + THREADS];
    __syncthreads();

    const unsigned colb = (unsigned)lane * 16u;   // byte offset of this lane's float4 in a D=256 row

    // ---- preamble: self/v/bias dots + self->cat, BEFORE the gather so these regs retire ----
    {
        const float4 b4 = *(const float4*)((const char*)bias + colb);
        #pragma unroll
        for (int rr = 0; rr < 2; ++rr) {
            const int r   = wave + rr * 4;
            const int row = row0 + r;
            const int nu  = __builtin_amdgcn_readfirstlane(nodes_u[row]);
            const int nv  = __builtin_amdgcn_readfirstlane(nodes_v[row]);
            const float4 self4 = *(const float4*)((const char*)u2e + (((unsigned)nu) << 10) + colb);
            const float4 v4    = *(const float4*)((const char*)v2e + (((unsigned)nv) << 10) + colb);
            *(float4*)(&cat_lds[r][4 * lane]) = self4;
            float sv = self4.x * v4.x + self4.y * v4.y + self4.z * v4.z + self4.w * v4.w;
            float bv = b4.x * v4.x + b4.y * v4.y + b4.z * v4.z + b4.w * v4.w;
            #pragma unroll
            for (int off = 32; off > 0; off >>= 1) {
                sv += __shfl_xor(sv, off, 64);
                bv += __shfl_xor(bv, off, 64);
            }
            if (lane == 0) { selfdot_lds[r] = sv; bdot_lds[r] = bv; }
        }
    }

    // ---- phase 1: dual-row merged gather. Wave w owns rows w and w+4 CONCURRENTLY:
    //      16 independent float4 loads in flight at every vmcnt wait (was 8).
    //      Masks are uniform (SALU) 0/1 floats -> single basic block, schedulable. ----
    const int rowA = row0 + wave, rowB = rowA + 4;
    const int cntA = __builtin_amdgcn_readfirstlane(neighbor_counts[rowA]);
    const int cntB = __builtin_amdgcn_readfirstlane(neighbor_counts[rowB]);
    const int itA = (cntA + 7) >> 3;
    const int itB = (cntB + 7) >> 3;
    const int itMin = itA < itB ? itA : itB;
    const int itMax = itA > itB ? itA : itB;
    const int baseA = wave * K_NB;
    const int baseB = baseA + 4 * K_NB;

#define LOAD8(P, BASE, KK)                                                          \
    const int4 P##ia = *(const int4*)&nbr_lds[(BASE) + (KK)];                       \
    const int4 P##ib = *(const int4*)&nbr_lds[(BASE) + (KK) + 4];                   \
    const float4 P##n0 = *(const float4*)((const char*)u2e + (((unsigned)P##ia.x) << 10) + colb); \
    const float4 P##n1 = *(const float4*)((const char*)u2e + (((unsigned)P##ia.y) << 10) + colb); \
    const float4 P##n2 = *(const float4*)((const char*)u2e + (((unsigned)P##ia.z) << 10) + colb); \
    const float4 P##n3 = *(const float4*)((const char*)u2e + (((unsigned)P##ia.w) << 10) + colb); \
    const float4 P##n4 = *(const float4*)((const char*)u2e + (((unsigned)P##ib.x) << 10) + colb); \
    const float4 P##n5 = *(const float4*)((const char*)u2e + (((unsigned)P##ib.y) << 10) + colb); \
    const float4 P##n6 = *(const float4*)((const char*)u2e + (((unsigned)P##ib.z) << 10) + colb); \
    const float4 P##n7 = *(const float4*)((const char*)u2e + (((unsigned)P##ib.w) << 10) + colb);

#define ACC8(P, ACC, CNT, KK)                                                       \
    {                                                                               \
        const float m0 = ((KK) + 0 < (CNT)) ? 1.f : 0.f;                            \
        const float m1 = ((KK) + 1 < (CNT)) ? 1.f : 0.f;                            \
        const float m2 = ((KK) + 2 < (CNT)) ? 1.f : 0.f;                            \
        const float m3 = ((KK) + 3 < (CNT)) ? 1.f : 0.f;                            \
        const float m4 = ((KK) + 4 < (CNT)) ? 1.f : 0.f;                            \
        const float m5 = ((KK) + 5 < (CNT)) ? 1.f : 0.f;                            \
        const float m6 = ((KK) + 6 < (CNT)) ? 1.f : 0.f;                            \
        const float m7 = ((KK) + 7 < (CNT)) ? 1.f : 0.f;                            \
        ACC.x += m0*P##n0.x + m1*P##n1.x + m2*P##n2.x + m3*P##n3.x                  \
               + m4*P##n4.x + m5*P##n5.x + m6*P##n6.x + m7*P##n7.x;                 \
        ACC.y += m0*P##n0.y + m1*P##n1.y + m2*P##n2.y + m3*P##n3.y                  \
               + m4*P##n4.y + m5*P##n5.y + m6*P##n6.y + m7*P##n7.y;                 \
        ACC.z += m0*P##n0.z + m1*P##n1.z + m2*P##n2.z + m3*P##n3.z                  \
               + m4*P##n4.z + m5*P##n5.z + m6*P##n6.z + m7*P##n7.z;                 \
        ACC.w += m0*P##n0.w + m1*P##n1.w + m2*P##n2.w + m3*P##n3.w                  \
               + m4*P##n4.w + m5*P##n5.w + m6*P##n6.w + m7*P##n7.w;                 \
    }

    float4 accA = make_float4(0.f, 0.f, 0.f, 0.f);
    float4 accB = make_float4(0.f, 0.f, 0.f, 0.f);

    // common part: both rows active -> 16 loads issued before first wait
    for (int i = 0; i < itMin; ++i) {
        const int k = i << 3;
        LOAD8(A, baseA, k)
        LOAD8(B, baseB, k)
        ACC8(A, accA, cntA, k)
        ACC8(B, accB, cntB, k)
    }
    // remainder: only the longer row (uniform selects, single code path, 8-deep)
    if (itMin < itMax) {
        const bool Along = itA > itB;
        const int  cntL  = Along ? cntA : cntB;
        const int  baseL = Along ? baseA : baseB;
        float4 accL = make_float4(0.f, 0.f, 0.f, 0.f);
        for (int i = itMin; i < itMax; ++i) {
            const int k = i << 3;
            LOAD8(L, baseL, k)
            ACC8(L, accL, cntL, k)
        }
        if (Along) {
            accA.x += accL.x; accA.y += accL.y; accA.z += accL.z; accA.w += accL.w;
        } else {
            accB.x += accL.x; accB.y += accL.y; accB.z += accL.z; accB.w += accL.w;
        }
    }
#undef LOAD8
#undef ACC8

    {
        const float invA = 1.0f / (float)(cntA > 0 ? cntA : 1);
        const float invB = 1.0f / (float)(cntB > 0 ? cntB : 1);
        *(float4*)(&cat_lds[wave][D_DIM + 4 * lane]) =
            make_float4(accA.x * invA, accA.y * invA, accA.z * invA, accA.w * invA);
        *(float4*)(&cat_lds[wave + 4][D_DIM + 4 * lane]) =
            make_float4(accB.x * invB, accB.y * invB, accB.z * invB, accB.w * invB);
    }
    __syncthreads();

    // ---- phase 2: t_j = sum_d W[d, j] * v[d]; thread t owns j = 2t, 2t+1 for all 8 rows ----
    unsigned voff[R_BLK];
    #pragma unroll
    for (int r = 0; r < R_BLK; ++r) {
        const int nv = __builtin_amdgcn_readfirstlane(nodes_v[row0 + r]);
        voff[r] = ((unsigned)nv) << 10;
    }

    float2 acc2[R_BLK];
    #pragma unroll
    for (int r = 0; r < R_BLK; ++r) acc2[r] = make_float2(0.f, 0.f);

    const unsigned tb8 = (unsigned)t * 8u;
    for (int d = 0; d < D_DIM; d += 4) {
        float4 vq[R_BLK];
        #pragma unroll
        for (int r = 0; r < R_BLK; ++r)
            vq[r] = *(const float4*)((const char*)v2e + voff[r] + (unsigned)d * 4u);

        #pragma unroll
        for (int dd = 0; dd < 4; ++dd) {
            const float2 wq = *(const float2*)((const char*)W + (((unsigned)(d + dd)) << 11) + tb8);
            #pragma unroll
            for (int r = 0; r < R_BLK; ++r) {
                const float vs = (dd == 0) ? vq[r].x : (dd == 1) ? vq[r].y
                               : (dd == 2) ? vq[r].z : vq[r].w;
                acc2[r].x += wq.x * vs;
                acc2[r].y += wq.y * vs;
            }
        }
    }

    // ---- epilogue: score = sum_j cat[j] * t_j  (+ b·v), reduce across block ----
    #pragma unroll
    for (int r = 0; r < R_BLK; ++r) {
        const float2 c2 = *(const float2*)(&cat_lds[r][2 * t]);
        float p = c2.x * acc2[r].x + c2.y * acc2[r].y;
        #pragma unroll
        for (int off = 32; off > 0; off >>= 1) p += __shfl_xor(p, off, 64);
        if (lane == 0) red_lds[r * 4 + wave] = p;
    }
    __syncthreads();

    if (t < R_BLK) {
        const int row = row0 + t;
        const int cnt = neighbor_counts[row];
        float s;
        if (cnt > 0) {
            s = red_lds[t * 4 + 0] + red_lds[t * 4 + 1]
              + red_lds[t * 4 + 2] + red_lds[t * 4 + 3] + bdot_lds[t];
        } else {
            s = selfdot_lds[t];
        }
        out[row] = s;
    }
}

extern "C" void kernel_launch(void* const* d_in, const int* in_sizes, int n_in,
                              void* d_out, int out_size, void* d_ws, size_t ws_size,
                              hipStream_t stream) {
    const int*   nodes_u         = (const int*)d_in[0];
    const int*   nodes_v         = (const int*)d_in[1];
    const int*   neighbors       = (const int*)d_in[2];
    const int*   neighbor_counts = (const int*)d_in[3];
    const float* u2e             = (const float*)d_in[4];
    const float* v2e             = (const float*)d_in[5];
    const float* W               = (const float*)d_in[6];
    const float* bias            = (const float*)d_in[7];
    float*       out             = (float*)d_out;

    const int blocks = B_ROWS / R_BLK;   // 2048
    easyrec_fused<<<blocks, THREADS, 0, stream>>>(
        nodes_u, nodes_v, neighbors, neighbor_counts, u2e, v2e, W, bias, out);
}

// Round 2
// 326.105 us; speedup vs baseline: 1.0037x; 1.0037x over previous
//
#include <hip/hip_runtime.h>

#define B_ROWS   16384
#define K_NB     64
#define D_DIM    256
#define TWO_D    512
#define R_BLK    8          // rows per block
#define THREADS  256

// __launch_bounds__(256, 4): license up to 128 VGPR so the 16-deep gather pipeline
// (16 live float4 destinations = 64 VGPRs) fits. sched_barrier(0) between the load
// group and the accumulate group FORCES the scheduler to keep all 16 in flight —
// round-1 showed source order alone gets silently re-serialized (VGPR stayed 44).
__global__ __launch_bounds__(THREADS, 4)
void easyrec_fused(const int* __restrict__ nodes_u,
                   const int* __restrict__ nodes_v,
                   const int* __restrict__ neighbors,
                   const int* __restrict__ neighbor_counts,
                   const float* __restrict__ u2e,
                   const float* __restrict__ v2e,
                   const float* __restrict__ W,      // [D, 2D] row-major
                   const float* __restrict__ bias,   // [D]
                   float* __restrict__ out)          // [B]
{
    __shared__ __align__(16) int   nbr_lds[R_BLK * K_NB];     // 2 KB
    __shared__ __align__(16) float cat_lds[R_BLK][TWO_D];     // 16 KB: [self | nmean]
    __shared__ float red_lds[R_BLK * 4];
    __shared__ float selfdot_lds[R_BLK];
    __shared__ float bdot_lds[R_BLK];

    const int t    = threadIdx.x;
    const int wave = t >> 6;
    const int lane = t & 63;
    const int row0 = blockIdx.x * R_BLK;

    // ---- stage neighbor indices for the 8 rows (512 ints, coalesced) ----
    nbr_lds[t]           = neighbors[(size_t)row0 * K_NB + t];
    nbr_lds[t + THREADS] = neighbors[(size_t)row0 * K_NB + t + THREADS];
    __syncthreads();

    const unsigned colb = (unsigned)lane * 16u;   // byte offset of this lane's float4 in a D=256 row

    // ---- preamble: self/v/bias dots + self->cat, BEFORE the gather so these regs retire ----
    {
        const float4 b4 = *(const float4*)((const char*)bias + colb);
        #pragma unroll
        for (int rr = 0; rr < 2; ++rr) {
            const int r   = wave + rr * 4;
            const int row = row0 + r;
            const int nu  = __builtin_amdgcn_readfirstlane(nodes_u[row]);
            const int nv  = __builtin_amdgcn_readfirstlane(nodes_v[row]);
            const float4 self4 = *(const float4*)((const char*)u2e + (((unsigned)nu) << 10) + colb);
            const float4 v4    = *(const float4*)((const char*)v2e + (((unsigned)nv) << 10) + colb);
            *(float4*)(&cat_lds[r][4 * lane]) = self4;
            float sv = self4.x * v4.x + self4.y * v4.y + self4.z * v4.z + self4.w * v4.w;
            float bv = b4.x * v4.x + b4.y * v4.y + b4.z * v4.z + b4.w * v4.w;
            #pragma unroll
            for (int off = 32; off > 0; off >>= 1) {
                sv += __shfl_xor(sv, off, 64);
                bv += __shfl_xor(bv, off, 64);
            }
            if (lane == 0) { selfdot_lds[r] = sv; bdot_lds[r] = bv; }
        }
    }

    // ---- phase 1: dual-row merged gather, sched_barrier-enforced 16-deep pipeline.
    //      Wave w owns rows w and w+4 concurrently; all 16 float4 loads of an
    //      iteration are forced to be in flight before the first accumulate. ----
    const int rowA = row0 + wave, rowB = rowA + 4;
    const int cntA = __builtin_amdgcn_readfirstlane(neighbor_counts[rowA]);
    const int cntB = __builtin_amdgcn_readfirstlane(neighbor_counts[rowB]);
    const int itA = (cntA + 7) >> 3;
    const int itB = (cntB + 7) >> 3;
    const int itMin = itA < itB ? itA : itB;
    const int itMax = itA > itB ? itA : itB;
    const int baseA = wave * K_NB;
    const int baseB = baseA + 4 * K_NB;

#define LOAD8(P, BASE, KK)                                                          \
    const int4 P##ia = *(const int4*)&nbr_lds[(BASE) + (KK)];                       \
    const int4 P##ib = *(const int4*)&nbr_lds[(BASE) + (KK) + 4];                   \
    const float4 P##n0 = *(const float4*)((const char*)u2e + (((unsigned)P##ia.x) << 10) + colb); \
    const float4 P##n1 = *(const float4*)((const char*)u2e + (((unsigned)P##ia.y) << 10) + colb); \
    const float4 P##n2 = *(const float4*)((const char*)u2e + (((unsigned)P##ia.z) << 10) + colb); \
    const float4 P##n3 = *(const float4*)((const char*)u2e + (((unsigned)P##ia.w) << 10) + colb); \
    const float4 P##n4 = *(const float4*)((const char*)u2e + (((unsigned)P##ib.x) << 10) + colb); \
    const float4 P##n5 = *(const float4*)((const char*)u2e + (((unsigned)P##ib.y) << 10) + colb); \
    const float4 P##n6 = *(const float4*)((const char*)u2e + (((unsigned)P##ib.z) << 10) + colb); \
    const float4 P##n7 = *(const float4*)((const char*)u2e + (((unsigned)P##ib.w) << 10) + colb);

#define ACC8(P, ACC, CNT, KK)                                                       \
    {                                                                               \
        const float m0 = ((KK) + 0 < (CNT)) ? 1.f : 0.f;                            \
        const float m1 = ((KK) + 1 < (CNT)) ? 1.f : 0.f;                            \
        const float m2 = ((KK) + 2 < (CNT)) ? 1.f : 0.f;                            \
        const float m3 = ((KK) + 3 < (CNT)) ? 1.f : 0.f;                            \
        const float m4 = ((KK) + 4 < (CNT)) ? 1.f : 0.f;                            \
        const float m5 = ((KK) + 5 < (CNT)) ? 1.f : 0.f;                            \
        const float m6 = ((KK) + 6 < (CNT)) ? 1.f : 0.f;                            \
        const float m7 = ((KK) + 7 < (CNT)) ? 1.f : 0.f;                            \
        ACC.x += m0*P##n0.x + m1*P##n1.x + m2*P##n2.x + m3*P##n3.x                  \
               + m4*P##n4.x + m5*P##n5.x + m6*P##n6.x + m7*P##n7.x;                 \
        ACC.y += m0*P##n0.y + m1*P##n1.y + m2*P##n2.y + m3*P##n3.y                  \
               + m4*P##n4.y + m5*P##n5.y + m6*P##n6.y + m7*P##n7.y;                 \
        ACC.z += m0*P##n0.z + m1*P##n1.z + m2*P##n2.z + m3*P##n3.z                  \
               + m4*P##n4.z + m5*P##n5.z + m6*P##n6.z + m7*P##n7.z;                 \
        ACC.w += m0*P##n0.w + m1*P##n1.w + m2*P##n2.w + m3*P##n3.w                  \
               + m4*P##n4.w + m5*P##n5.w + m6*P##n6.w + m7*P##n7.w;                 \
    }

    float4 accA = make_float4(0.f, 0.f, 0.f, 0.f);
    float4 accB = make_float4(0.f, 0.f, 0.f, 0.f);

    // common part: both rows active -> 16 loads FORCED in flight before first acc.
    for (int i = 0; i < itMin; ++i) {
        const int k = i << 3;
        LOAD8(A, baseA, k)
        LOAD8(B, baseB, k)
        __builtin_amdgcn_sched_barrier(0);   // loads may not sink below; accs may not hoist above
        ACC8(A, accA, cntA, k)
        ACC8(B, accB, cntB, k)
    }
    // remainder: only the longer row (uniform selects, single code path, 8-deep)
    if (itMin < itMax) {
        const bool Along = itA > itB;
        const int  cntL  = Along ? cntA : cntB;
        const int  baseL = Along ? baseA : baseB;
        float4 accL = make_float4(0.f, 0.f, 0.f, 0.f);
        for (int i = itMin; i < itMax; ++i) {
            const int k = i << 3;
            LOAD8(L, baseL, k)
            __builtin_amdgcn_sched_barrier(0);
            ACC8(L, accL, cntL, k)
        }
        if (Along) {
            accA.x += accL.x; accA.y += accL.y; accA.z += accL.z; accA.w += accL.w;
        } else {
            accB.x += accL.x; accB.y += accL.y; accB.z += accL.z; accB.w += accL.w;
        }
    }
#undef LOAD8
#undef ACC8

    {
        const float invA = 1.0f / (float)(cntA > 0 ? cntA : 1);
        const float invB = 1.0f / (float)(cntB > 0 ? cntB : 1);
        *(float4*)(&cat_lds[wave][D_DIM + 4 * lane]) =
            make_float4(accA.x * invA, accA.y * invA, accA.z * invA, accA.w * invA);
        *(float4*)(&cat_lds[wave + 4][D_DIM + 4 * lane]) =
            make_float4(accB.x * invB, accB.y * invB, accB.z * invB, accB.w * invB);
    }
    __syncthreads();

    // ---- phase 2: t_j = sum_d W[d, j] * v[d]; thread t owns j = 2t, 2t+1 for all 8 rows ----
    unsigned voff[R_BLK];
    #pragma unroll
    for (int r = 0; r < R_BLK; ++r) {
        const int nv = __builtin_amdgcn_readfirstlane(nodes_v[row0 + r]);
        voff[r] = ((unsigned)nv) << 10;
    }

    float2 acc2[R_BLK];
    #pragma unroll
    for (int r = 0; r < R_BLK; ++r) acc2[r] = make_float2(0.f, 0.f);

    const unsigned tb8 = (unsigned)t * 8u;
    for (int d = 0; d < D_DIM; d += 4) {
        float4 vq[R_BLK];
        #pragma unroll
        for (int r = 0; r < R_BLK; ++r)
            vq[r] = *(const float4*)((const char*)v2e + voff[r] + (unsigned)d * 4u);

        #pragma unroll
        for (int dd = 0; dd < 4; ++dd) {
            const float2 wq = *(const float2*)((const char*)W + (((unsigned)(d + dd)) << 11) + tb8);
            #pragma unroll
            for (int r = 0; r < R_BLK; ++r) {
                const float vs = (dd == 0) ? vq[r].x : (dd == 1) ? vq[r].y
                               : (dd == 2) ? vq[r].z : vq[r].w;
                acc2[r].x += wq.x * vs;
                acc2[r].y += wq.y * vs;
            }
        }
    }

    // ---- epilogue: score = sum_j cat[j] * t_j  (+ b·v), reduce across block ----
    #pragma unroll
    for (int r = 0; r < R_BLK; ++r) {
        const float2 c2 = *(const float2*)(&cat_lds[r][2 * t]);
        float p = c2.x * acc2[r].x + c2.y * acc2[r].y;
        #pragma unroll
        for (int off = 32; off > 0; off >>= 1) p += __shfl_xor(p, off, 64);
        if (lane == 0) red_lds[r * 4 + wave] = p;
    }
    __syncthreads();

    if (t < R_BLK) {
        const int row = row0 + t;
        const int cnt = neighbor_counts[row];
        float s;
        if (cnt > 0) {
            s = red_lds[t * 4 + 0] + red_lds[t * 4 + 1]
              + red_lds[t * 4 + 2] + red_lds[t * 4 + 3] + bdot_lds[t];
        } else {
            s = selfdot_lds[t];
        }
        out[row] = s;
    }
}

extern "C" void kernel_launch(void* const* d_in, const int* in_sizes, int n_in,
                              void* d_out, int out_size, void* d_ws, size_t ws_size,
                              hipStream_t stream) {
    const int*   nodes_u         = (const int*)d_in[0];
    const int*   nodes_v         = (const int*)d_in[1];
    const int*   neighbors       = (const int*)d_in[2];
    const int*   neighbor_counts = (const int*)d_in[3];
    const float* u2e             = (const float*)d_in[4];
    const float* v2e             = (const float*)d_in[5];
    const float* W               = (const float*)d_in[6];
    const float* bias            = (const float*)d_in[7];
    float*       out             = (float*)d_out;

    const int blocks = B_ROWS / R_BLK;   // 2048
    easyrec_fused<<<blocks, THREADS, 0, stream>>>(
        nodes_u, nodes_v, neighbors, neighbor_counts, u2e, v2e, W, bias, out);
}